// Round 14
// baseline (699.091 us; speedup 1.0000x reference)
//
#include <hip/hip_runtime.h>
#include <hip/hip_fp16.h>

typedef _Float16 f16x8 __attribute__((ext_vector_type(8)));
typedef float f32x4 __attribute__((ext_vector_type(4)));

#define NN 65536
#define KK 2048
#define DD 64

__device__ __forceinline__ unsigned int fkey(float f) {
  unsigned int u = __float_as_uint(f);
  return (u & 0x80000000u) ? ~u : (u | 0x80000000u);
}

// --- K1: normalize codebook -> cbT32[64][2048], cbRM[2048][64], cn2, fp16 frags ---
// cb frag layout (f16 units): idx = s*65536 + c*32 + g2*8 + i  (s=k>>5, g2=(k>>3)&3, i=k&7)
__global__ void k_norm_cb(const float* __restrict__ cb, float* __restrict__ cbT32,
                          float* __restrict__ cbRM, float* __restrict__ cn2,
                          unsigned short* __restrict__ Bhi) {
  int gid = blockIdx.x * blockDim.x + threadIdx.x;
  int c = gid >> 6;   // codebook row, one wave per row
  int k = gid & 63;   // dim
  float v = cb[c * DD + k];
  float ss = v * v;
  #pragma unroll
  for (int o = 32; o; o >>= 1) ss += __shfl_xor(ss, o);
  float inv = 1.0f / fmaxf(sqrtf(ss), 1e-12f);
  float cn = v * inv;
  cbT32[k * KK + c] = cn;
  cbRM[c * DD + k] = cn;
  float s2 = cn * cn;
  #pragma unroll
  for (int o = 32; o; o >>= 1) s2 += __shfl_xor(s2, o);
  if (k == 0) cn2[c] = s2;
  _Float16 hh = (_Float16)(cn * 256.0f);
  int s = k >> 5, g2 = (k >> 3) & 3, i = k & 7;
  Bhi[s * 65536 + c * 32 + g2 * 8 + i] = *(unsigned short*)&hh;
}

// --- K2: normalize z rows -> fp16 frags + znRM[n][64] fp32 ---
// z frag layout (f16x8 units): idx = (rt*2+s)*64 + g2*16 + r
__global__ void k_norm_z(const float* __restrict__ z,
                         unsigned short* __restrict__ Ahi,
                         float* __restrict__ znRM) {
  __shared__ float np_[8][32];
  __shared__ float invS[32];
  int t = threadIdx.x;
  int r32 = t & 31, q = t >> 5;  // row-in-32, k-chunk (8 k each)
  int n0 = blockIdx.x * 32;
  int w0 = n0 & 63, hh = (n0 >> 6) & 63, bb = n0 >> 12;
  const float* src = z + (size_t)bb * 262144 + (size_t)q * 8 * 4096 + hh * 64 + w0 + r32;
  float v[8];
  float ss = 0.f;
  #pragma unroll
  for (int i = 0; i < 8; ++i) {
    float x = src[(size_t)i * 4096];
    v[i] = x;
    ss = fmaf(x, x, ss);
  }
  np_[q][r32] = ss;
  __syncthreads();
  if (t < 32) {
    float s = 0.f;
    #pragma unroll
    for (int qq = 0; qq < 8; ++qq) s += np_[qq][t];
    invS[t] = 1.0f / fmaxf(sqrtf(s), 1e-12f);
  }
  __syncthreads();
  float inv = invS[r32];
  float zr[8];
  union { _Float16 h[8]; uint4 u; } hi;
  #pragma unroll
  for (int i = 0; i < 8; ++i) {
    zr[i] = v[i] * inv;
    hi.h[i] = (_Float16)(zr[i] * 256.0f);
  }
  float* zd = znRM + (size_t)(n0 + r32) * 64 + q * 8;
  *(f32x4*)zd = (f32x4){zr[0], zr[1], zr[2], zr[3]};
  *(f32x4*)(zd + 4) = (f32x4){zr[4], zr[5], zr[6], zr[7]};
  int rt = (n0 + r32) >> 4;
  int r = r32 & 15;
  int s = q >> 2, g2 = q & 3;
  ((uint4*)Ahi)[(size_t)(rt * 2 + s) * 64 + g2 * 16 + r] = hi.u;
}

// exact distance (double accumulation) for argmin candidates
__device__ __forceinline__ unsigned long long exact_key(
    const float* __restrict__ znr, const float* __restrict__ cbRM,
    const float* __restrict__ cn2g, int col) {
  const float* cbr = cbRM + col * 64;
  double s = 0.0;
  #pragma unroll 8
  for (int k = 0; k < 64; ++k) s = fma((double)znr[k], (double)cbr[k], s);
  float dex = fmaf(-2.0f, (float)s, cn2g[col]);
  return ((unsigned long long)fkey(dex) << 32) | (unsigned)col;
}

// --- K3: fp16-hi MFMA + argmin(exact re-check) + softmax + prob/q + loss ---
// prob drain uses ALIGNMENT-PEELED full-line x4 stores: prob byte base ≡ 12
// mod 128, so peel 29 head + 3 tail floats; the 4088 remaining x4 chunks are
// 16B-aligned and each wave instr covers exactly 8 whole 128B lines (the
// fill-kernel pattern measured clean at 6.7 TB/s on this same buffer).
__global__ __launch_bounds__(512, 4) void k_main(
    const f16x8* __restrict__ Ahi, const f16x8* __restrict__ Bhi,
    const float* __restrict__ cn2g, const float* __restrict__ cbT32,
    const float* __restrict__ cbRM, const float* __restrict__ znRM,
    float* __restrict__ qout, float* __restrict__ prob,
    float* __restrict__ partials) {
  __shared__ float eF[8 * 2056];  // flat flip buffer, row stride 2056 (bank-shift 8)
  __shared__ unsigned long long keyS[16];
  __shared__ unsigned long long keyExS[16];
  __shared__ float rowpart[16][8];
  __shared__ float rowInv[16];
  __shared__ float dminS[16];
  __shared__ float wsum[8];

  int t = threadIdx.x;
  int lane = t & 63, wv = t >> 6;
  int l15 = lane & 15, g = lane >> 4;
  int rt = blockIdx.x;
  int n0 = rt * 16;
  int wc0 = wv * 256;

  if (t < 16) { keyS[t] = ~0ull; keyExS[t] = ~0ull; }

  // z fragments (B-operand): z-row = l15, k-chunk = g, half = s
  f16x8 z_hi[2];
  {
    size_t base = (size_t)rt * 128 + (size_t)g * 16 + l15;
    z_hi[0] = Ahi[base];
    z_hi[1] = Ahi[base + 64];
  }

  f32x4 acc[16];
  #pragma unroll
  for (int i = 0; i < 16; ++i) acc[i] = (f32x4){0.f, 0.f, 0.f, 0.f};

  // cb frag stream, depth-4 prefetch. idx(f16x8) = s*8192 + t8*64 + b0
  int b0 = (wc0 + l15) * 4 + g;
  f16x8 bf[4];
  #pragma unroll
  for (int i = 0; i < 4; ++i)
    bf[i] = Bhi[(i & 1) * 8192 + (i >> 1) * 64 + b0];
  #pragma unroll
  for (int p = 0; p < 32; ++p) {  // p = t8*2 + s, t8 in 0..15
    f16x8 cur = bf[p & 3];
    if (p < 28) {
      int pn = p + 4;
      bf[p & 3] = Bhi[(pn & 1) * 8192 + (pn >> 1) * 64 + b0];
    }
    acc[p >> 1] = __builtin_amdgcn_mfma_f32_16x16x32_f16(cur, z_hi[p & 1], acc[p >> 1], 0, 0, 0);
  }

  // epilogue: d ~= cn2 - 2*acc*2^-16 (|err|<2e-3); approx argmin key; e=exp(-d)
  unsigned long long kminH = ~0ull;
  float esumT = 0.f;
  int cb0 = wc0 + g * 4;
  #pragma unroll
  for (int t8 = 0; t8 < 16; ++t8) {
    int c0 = cb0 + t8 * 16;
    float4 c4 = *(const float4*)(cn2g + c0);
    float cn[4] = {c4.x, c4.y, c4.z, c4.w};
    #pragma unroll
    for (int r = 0; r < 4; ++r) {
      float d = fmaf(acc[t8][r], -3.0517578125e-05f, cn[r]);
      unsigned long long kk = ((unsigned long long)fkey(d) << 32) | (unsigned)(c0 + r);
      if (kk < kminH) kminH = kk;
      float e = __expf(-d);
      acc[t8][r] = e;
      esumT += e;
    }
  }
  // combine 4 g-groups sharing one z-row (lanes l15, +16, +32, +48)
  #pragma unroll
  for (int o = 16; o <= 32; o <<= 1) {
    esumT += __shfl_xor(esumT, o);
    unsigned long long ok = __shfl_xor(kminH, o);
    if (ok < kminH) kminH = ok;
  }
  __syncthreads();  // keyS init visible
  if (lane < 16) {
    rowpart[l15][wv] = esumT;
    atomicMin(&keyS[l15], kminH);
  }
  __syncthreads();
  if (t < 16) {
    float s = 0.f;
    #pragma unroll
    for (int w = 0; w < 8; ++w) s += rowpart[t][w];
    rowInv[t] = 1.0f / s;
    unsigned int u = (unsigned int)(keyS[t] >> 32);
    dminS[t] = (u & 0x80000000u) ? __uint_as_float(u & 0x7fffffffu)
                                 : __uint_as_float(~u);
  }
  __syncthreads();

  // prob: two 8-row flip sweeps; drain with alignment-peeled full-line x4 stores
  float invR = rowInv[l15];
  #pragma unroll
  for (int half = 0; half < 2; ++half) {
    if ((l15 >> 3) == half) {
      int rl = l15 & 7;
      #pragma unroll
      for (int t8 = 0; t8 < 16; ++t8)
        *(f32x4*)&eF[rl * 2056 + wc0 + t8 * 16 + g * 4] = acc[t8] * invR;
    }
    __syncthreads();
    {
      float* G = prob + (size_t)(n0 + half * 8) * KK;  // byte ≡ 12 mod 128
      if (t < 32) {  // peel: 29 head + 3 tail scalars
        int j = (t < 29) ? t : (16384 - 32 + t);
        int r = j >> 11, c = j & 2047;
        G[j] = eF[r * 2056 + c];
      }
      #pragma unroll
      for (int it = 0; it < 8; ++it) {  // 4088 aligned x4 chunks
        int ch = it * 512 + t;
        if (ch < 4088) {
          int j0 = 29 + ch * 4;  // byte(G+j0) ≡ 0 mod 16; wave span = 8 full lines
          int r = j0 >> 11, c = j0 & 2047;
          int i0 = r * 2056 + c;
          f32x4 v;
          v[0] = eF[i0];
          v[1] = eF[(c + 1 < 2048) ? i0 + 1 : (r + 1) * 2056 + 0];
          v[2] = eF[(c + 2 < 2048) ? i0 + 2 : (r + 1) * 2056 + (c + 2 - 2048)];
          v[3] = eF[(c + 3 < 2048) ? i0 + 3 : (r + 1) * 2056 + (c + 3 - 2048)];
          *(f32x4*)(G + j0) = v;
        }
      }
    }
    __syncthreads();
  }

  // exact argmin re-check: candidates have e >= exp(-(dmin+margin)), margin 8e-3
  // (VALU work drains under the store burst)
  {
    const float* znr = znRM + (size_t)(n0 + l15) * 64;
    float eTh = __expf(-dminS[l15] - 0.008f) * 0.995f;
    unsigned long long kex = ~0ull;
    #pragma unroll
    for (int t8 = 0; t8 < 16; ++t8) {
      int c0 = cb0 + t8 * 16;
      #pragma unroll
      for (int r = 0; r < 4; ++r)
        if (acc[t8][r] >= eTh) {
          unsigned long long kk = exact_key(znr, cbRM, cn2g, c0 + r);
          if (kk < kex) kex = kk;
        }
    }
    #pragma unroll
    for (int o = 16; o <= 32; o <<= 1) {
      unsigned long long ok = __shfl_xor(kex, o);
      if (ok < kex) kex = ok;
    }
    if (lane < 16) atomicMin(&keyExS[l15], kex);
  }
  __syncthreads();

  // q gather/write + SSD partial
  {
    float ssd = 0.f;
    #pragma unroll
    for (int i = 0; i < 2; ++i) {
      int e = i * 512 + t;       // 0..1023 over (d, wi)
      int d = e >> 4, wi = e & 15;
      int cw = (int)(keyExS[wi] & 0xffffffffull);
      float qv = cbT32[d * KK + cw];
      int w0 = n0 & 63, hh2 = (n0 >> 6) & 63, bb = n0 >> 12;
      qout[((size_t)((bb << 6) | d) * 64 + hh2) * 64 + w0 + wi] = qv;
      float zn = znRM[(size_t)(n0 + wi) * 64 + d];
      float df = qv - zn;
      ssd = fmaf(df, df, ssd);
    }
    #pragma unroll
    for (int o = 32; o; o >>= 1) ssd += __shfl_xor(ssd, o);
    if (lane == 0) wsum[wv] = ssd;
  }
  __syncthreads();
  if (t == 0) {
    float s = 0.f;
    #pragma unroll
    for (int w = 0; w < 8; ++w) s += wsum[w];
    partials[blockIdx.x] = s;
  }
}

// --- K4: deterministic loss reduction ---
__global__ void k_final(const float* __restrict__ partials, float* __restrict__ out) {
  __shared__ float wsh[4];
  int t = threadIdx.x;
  float s = 0.f;
  for (int i = 0; i < 16; ++i) s += partials[t * 16 + i];
  #pragma unroll
  for (int o = 32; o; o >>= 1) s += __shfl_xor(s, o);
  if ((t & 63) == 0) wsh[t >> 6] = s;
  __syncthreads();
  if (t == 0) {
    float tot = (wsh[0] + wsh[1]) + (wsh[2] + wsh[3]);
    float cbl = tot * (1.0f / 4194304.0f);  // mean over n*d
    out[4194304] = 1.25f * cbl;  // loss = cb + 0.25*commit (commit == cb numerically)
    out[4194305] = cbl;
    out[4194306] = cbl;
  }
}

extern "C" void kernel_launch(void* const* d_in, const int* in_sizes, int n_in,
                              void* d_out, int out_size, void* d_ws, size_t ws_size,
                              hipStream_t stream) {
  const float* z = (const float*)d_in[0];
  const float* cb = (const float*)d_in[1];
  float* out = (float*)d_out;
  char* ws = (char*)d_ws;

  float* cbT32 = (float*)(ws);                           // 524288 B
  float* cbRM = (float*)(ws + 524288);                   // 524288 B
  float* cn2 = (float*)(ws + 1048576);                   // 8192 B
  unsigned short* Bhi = (unsigned short*)(ws + 1056768); // 262144 B
  float* partials = (float*)(ws + 1318912);              // 16384 B
  unsigned short* Ahi = (unsigned short*)(ws + 1335296); // 8 MB
  float* znRM = (float*)(ws + 9723904);                  // 16 MB

  k_norm_cb<<<512, 256, 0, stream>>>(cb, cbT32, cbRM, cn2, Bhi);
  k_norm_z<<<2048, 256, 0, stream>>>(z, Ahi, znRM);
  k_main<<<4096, 512, 0, stream>>>((const f16x8*)Ahi, (const f16x8*)Bhi,
                                   cn2, cbT32, cbRM, znRM,
                                   out, out + 4194307, partials);
  k_final<<<1, 256, 0, stream>>>(partials, out);
}

// Round 15
// 294.335 us; speedup vs baseline: 2.3752x; 2.3752x over previous
//
#include <hip/hip_runtime.h>
#include <hip/hip_fp16.h>

typedef _Float16 f16x8 __attribute__((ext_vector_type(8)));
typedef float f32x4 __attribute__((ext_vector_type(4)));

#define NN 65536
#define KK 2048
#define DD 64

__device__ __forceinline__ unsigned int fkey(float f) {
  unsigned int u = __float_as_uint(f);
  return (u & 0x80000000u) ? ~u : (u | 0x80000000u);
}

// --- K1: normalize codebook -> cbT32[64][2048], cn2[2048], fp16-split frags ---
// cb frag layout (f16 units): idx = s*65536 + c*32 + g2*8 + i  (s=k>>5, g2=(k>>3)&3, i=k&7)
__global__ void k_norm_cb(const float* __restrict__ cb, float* __restrict__ cbT32,
                          float* __restrict__ cn2,
                          unsigned short* __restrict__ Bhi,
                          unsigned short* __restrict__ Blo) {
  int gid = blockIdx.x * blockDim.x + threadIdx.x;
  int c = gid >> 6;   // codebook row, one wave per row
  int k = gid & 63;   // dim
  float v = cb[c * DD + k];
  float ss = v * v;
  #pragma unroll
  for (int o = 32; o; o >>= 1) ss += __shfl_xor(ss, o);
  float inv = 1.0f / fmaxf(sqrtf(ss), 1e-12f);
  float cn = v * inv;
  cbT32[k * KK + c] = cn;
  float s2 = cn * cn;
  #pragma unroll
  for (int o = 32; o; o >>= 1) s2 += __shfl_xor(s2, o);
  if (k == 0) cn2[c] = s2;
  // fp16 split: cn*256 = hh + hl/4096  (both fp16-normal ranged)
  float sh = cn * 256.0f;
  _Float16 hh = (_Float16)sh;
  float resid = sh - (float)hh;
  _Float16 hl = (_Float16)(resid * 4096.0f);
  int s = k >> 5, g2 = (k >> 3) & 3, i = k & 7;
  int idx = s * 65536 + c * 32 + g2 * 8 + i;
  Bhi[idx] = *(unsigned short*)&hh;
  Blo[idx] = *(unsigned short*)&hl;
}

// --- K2: normalize z rows -> fp16-split z frags ---
// z frag layout (f16x8 units): idx = (rt*2+s)*64 + g2*16 + r
__global__ void k_norm_z(const float* __restrict__ z,
                         unsigned short* __restrict__ Ahi,
                         unsigned short* __restrict__ Alo) {
  __shared__ float np_[8][32];
  __shared__ float invS[32];
  int t = threadIdx.x;
  int r32 = t & 31, q = t >> 5;  // row-in-32, k-chunk (8 k each)
  int n0 = blockIdx.x * 32;
  int w0 = n0 & 63, hh = (n0 >> 6) & 63, bb = n0 >> 12;
  const float* src = z + (size_t)bb * 262144 + (size_t)q * 8 * 4096 + hh * 64 + w0 + r32;
  float v[8];
  float ss = 0.f;
  #pragma unroll
  for (int i = 0; i < 8; ++i) {
    float x = src[(size_t)i * 4096];
    v[i] = x;
    ss = fmaf(x, x, ss);
  }
  np_[q][r32] = ss;
  __syncthreads();
  if (t < 32) {
    float s = 0.f;
    #pragma unroll
    for (int qq = 0; qq < 8; ++qq) s += np_[qq][t];
    invS[t] = 1.0f / fmaxf(sqrtf(s), 1e-12f);
  }
  __syncthreads();
  float inv = invS[r32] * 256.0f;
  union { _Float16 h[8]; uint4 u; } hi, lo;
  #pragma unroll
  for (int i = 0; i < 8; ++i) {
    float sh = v[i] * inv;
    _Float16 a = (_Float16)sh;
    hi.h[i] = a;
    lo.h[i] = (_Float16)((sh - (float)a) * 4096.0f);
  }
  int rt = (n0 + r32) >> 4;
  int r = r32 & 15;
  int s = q >> 2, g2 = q & 3;
  size_t idx = (size_t)(rt * 2 + s) * 64 + g2 * 16 + r;
  ((uint4*)Ahi)[idx] = hi.u;
  ((uint4*)Alo)[idx] = lo.u;
}

// --- K3: MFMA GEMM (R8 structure) + argmin + softmax + q/loss, prob stores LAST ---
// 512 threads / 8 waves; 16 rows x 2048 cols via two col-half passes; pass-0 e
// parked in LDS fp16. The prob store burst is the FINAL phase of the block so
// no in-block scattered reads (q-gather) contend with the draining write lines
// (measured: concurrent scattered reads -> half-dirty evictions -> WRITE x2-3).
__global__ __launch_bounds__(512, 4) void k_main(
    const f16x8* __restrict__ Ahi, const f16x8* __restrict__ Alo,
    const f16x8* __restrict__ Bhi, const f16x8* __restrict__ Blo,
    const float* __restrict__ cn2g, const float* __restrict__ cbT32,
    float* __restrict__ qout, float* __restrict__ prob,
    float* __restrict__ partials) {
  __shared__ __half ehS[16][1032];  // pass-0 e (fp16), padded stride
  __shared__ unsigned long long keyS[16];
  __shared__ float rowpart[16][8];
  __shared__ float rowInv[16];
  __shared__ float wsum[8];

  int t = threadIdx.x;
  int lane = t & 63, wv = t >> 6;  // wv 0..7
  int l15 = lane & 15, g = lane >> 4;
  int rt = blockIdx.x;
  int n0 = rt * 16;

  if (t < 16) keyS[t] = ~0ull;

  // z fragments (B-operand): z-row = l15, k-chunk = g, half = s
  f16x8 z_hi[2], z_lo[2];
  {
    size_t base = (size_t)rt * 128 + (size_t)g * 16 + l15;
    z_hi[0] = Ahi[base];      z_hi[1] = Ahi[base + 64];
    z_lo[0] = Alo[base];      z_lo[1] = Alo[base + 64];
  }

  f32x4 acc1[8];
  unsigned long long kmin = ~0ull;
  float esumT = 0.f;

  #pragma unroll
  for (int pass = 0; pass < 2; ++pass) {
    int wc0 = pass * 1024 + wv * 128;
    #pragma unroll
    for (int i = 0; i < 8; ++i) acc1[i] = (f32x4){0.f, 0.f, 0.f, 0.f};
    f32x4 acc2t = (f32x4){0.f, 0.f, 0.f, 0.f};

    // cb frag stream (A-operand): idx(f16x8) = s*8192 + t8*64 + (wc0+l15)*4 + g
    int b0 = (wc0 + l15) * 4 + g;
    f16x8 bhA = Bhi[b0], blA = Blo[b0];
    f16x8 bhB, blB;
    #pragma unroll
    for (int p = 0; p < 16; ++p) {  // p = t8*2 + s
      int t8 = p >> 1, s = p & 1;
      if (p < 15) {
        int pn = p + 1;
        int idxn = (pn & 1) * 8192 + (pn >> 1) * 64 + b0;
        if (p & 1) { bhA = Bhi[idxn]; blA = Blo[idxn]; }
        else       { bhB = Bhi[idxn]; blB = Blo[idxn]; }
      }
      f16x8 bh = (p & 1) ? bhB : bhA;  // cb_hi
      f16x8 bl = (p & 1) ? blB : blA;  // cb_lo
      acc2t    = __builtin_amdgcn_mfma_f32_16x16x32_f16(bh, z_lo[s], acc2t, 0, 0, 0);
      acc1[t8] = __builtin_amdgcn_mfma_f32_16x16x32_f16(bh, z_hi[s], acc1[t8], 0, 0, 0);
      acc2t    = __builtin_amdgcn_mfma_f32_16x16x32_f16(bl, z_hi[s], acc2t, 0, 0, 0);
      if (s == 1) {  // tile complete: fold low-order correction
        acc1[t8] += acc2t * 2.44140625e-04f;  // 2^-12
        acc2t = (f32x4){0.f, 0.f, 0.f, 0.f};
      }
    }

    // per-pass epilogue: d = cn2 - 2*acc1*2^-16; exact u64 argmin; e = exp(-d)
    int cb0 = wc0 + g * 4;
    #pragma unroll
    for (int t8 = 0; t8 < 8; ++t8) {
      int c0 = cb0 + t8 * 16;
      float4 c4 = *(const float4*)(cn2g + c0);
      float cn[4] = {c4.x, c4.y, c4.z, c4.w};
      #pragma unroll
      for (int r = 0; r < 4; ++r) {
        float d = fmaf(acc1[t8][r], -3.0517578125e-05f, cn[r]);  // -2*2^-16
        unsigned long long kk = ((unsigned long long)fkey(d) << 32) | (unsigned)(c0 + r);
        if (kk < kmin) kmin = kk;
        float e = __expf(-d);
        acc1[t8][r] = e;
        esumT += e;
      }
    }
    if (pass == 0) {  // park e in LDS fp16
      #pragma unroll
      for (int t8 = 0; t8 < 8; ++t8) {
        int off = wv * 128 + t8 * 16 + g * 4;
        *(__half2*)&ehS[l15][off]     = __floats2half2_rn(acc1[t8][0], acc1[t8][1]);
        *(__half2*)&ehS[l15][off + 2] = __floats2half2_rn(acc1[t8][2], acc1[t8][3]);
      }
    }
  }

  // combine 4 g-groups sharing one z-row (lanes l15, +16, +32, +48)
  #pragma unroll
  for (int o = 16; o <= 32; o <<= 1) {
    esumT += __shfl_xor(esumT, o);
    unsigned long long ok = __shfl_xor(kmin, o);
    if (ok < kmin) kmin = ok;
  }
  __syncthreads();  // keyS init visible
  if (lane < 16) {
    rowpart[l15][wv] = esumT;
    atomicMin(&keyS[l15], kmin);
  }
  __syncthreads();
  if (t < 16) {
    float s = 0.f;
    #pragma unroll
    for (int w = 0; w < 8; ++w) s += rowpart[t][w];
    rowInv[t] = 1.0f / s;
  }
  __syncthreads();

  // q gather/write + SSD partial FIRST (scattered reads finish before the burst)
  {
    float ssd = 0.f;
    #pragma unroll
    for (int i = 0; i < 2; ++i) {
      int e = i * 512 + t;       // 0..1023 over (d, wi)
      int d = e >> 4, wi = e & 15;
      int cw = (int)(keyS[wi] & 0xffffffffull);
      float qv = cbT32[d * KK + cw];
      int w0 = n0 & 63, hh2 = (n0 >> 6) & 63, bb = n0 >> 12;
      qout[((size_t)((bb << 6) | d) * 64 + hh2) * 64 + w0 + wi] = qv;
      size_t aidx = ((size_t)(rt * 2 + (d >> 5)) * 64 + ((d >> 3) & 3) * 16 + wi) * 8 + (d & 7);
      float ah = (float)((const _Float16*)Ahi)[aidx];
      float al = (float)((const _Float16*)Alo)[aidx];
      float zn = fmaf(al, 2.44140625e-04f, ah) * 3.90625e-03f;  // (ah+al/4096)/256
      float df = qv - zn;
      ssd = fmaf(df, df, ssd);
    }
    #pragma unroll
    for (int o = 32; o; o >>= 1) ssd += __shfl_xor(ssd, o);
    if (lane == 0) wsum[wv] = ssd;
  }
  __syncthreads();
  if (t == 0) {
    float s = 0.f;
    #pragma unroll
    for (int w = 0; w < 8; ++w) s += wsum[w];
    partials[blockIdx.x] = s;
  }

  // prob stores LAST: direct cached dwordx4 (pass1 from regs, pass0 from LDS).
  // Fire-and-forget; drains under the next block's sequential K-loop.
  {
    float inv = rowInv[l15];
    float* pr = prob + (size_t)(n0 + l15) * KK + wv * 128 + g * 4;
    #pragma unroll
    for (int t8 = 0; t8 < 8; ++t8)
      *(f32x4*)(pr + 1024 + t8 * 16) = acc1[t8] * inv;
    #pragma unroll
    for (int t8 = 0; t8 < 8; ++t8) {
      int off = wv * 128 + t8 * 16 + g * 4;
      __half2 a = *(__half2*)&ehS[l15][off];
      __half2 b = *(__half2*)&ehS[l15][off + 2];
      f32x4 o4;
      o4[0] = __low2float(a) * inv;
      o4[1] = __high2float(a) * inv;
      o4[2] = __low2float(b) * inv;
      o4[3] = __high2float(b) * inv;
      *(f32x4*)(pr + t8 * 16) = o4;
    }
  }
}

// --- K4: deterministic loss reduction ---
__global__ void k_final(const float* __restrict__ partials, float* __restrict__ out) {
  __shared__ float wsh[4];
  int t = threadIdx.x;
  float s = 0.f;
  for (int i = 0; i < 16; ++i) s += partials[t * 16 + i];
  #pragma unroll
  for (int o = 32; o; o >>= 1) s += __shfl_xor(s, o);
  if ((t & 63) == 0) wsh[t >> 6] = s;
  __syncthreads();
  if (t == 0) {
    float tot = (wsh[0] + wsh[1]) + (wsh[2] + wsh[3]);
    float cbl = tot * (1.0f / 4194304.0f);  // mean over n*d
    out[4194304] = 1.25f * cbl;  // loss = cb + 0.25*commit (commit == cb numerically)
    out[4194305] = cbl;
    out[4194306] = cbl;
  }
}

extern "C" void kernel_launch(void* const* d_in, const int* in_sizes, int n_in,
                              void* d_out, int out_size, void* d_ws, size_t ws_size,
                              hipStream_t stream) {
  const float* z = (const float*)d_in[0];
  const float* cb = (const float*)d_in[1];
  float* out = (float*)d_out;
  char* ws = (char*)d_ws;

  float* cbT32 = (float*)(ws);                          // 524288 B
  float* cn2 = (float*)(ws + 524288);                   // 8192 B
  unsigned short* Bhi = (unsigned short*)(ws + 532480); // 262144 B
  unsigned short* Blo = (unsigned short*)(ws + 794624); // 262144 B
  float* partials = (float*)(ws + 1056768);             // 16384 B
  unsigned short* Ahi = (unsigned short*)(ws + 1073152);   // 8 MB
  unsigned short* Alo = (unsigned short*)(ws + 9461760);   // 8 MB

  k_norm_cb<<<512, 256, 0, stream>>>(cb, cbT32, cn2, Bhi, Blo);
  k_norm_z<<<2048, 256, 0, stream>>>(z, Ahi, Alo);
  k_main<<<4096, 512, 0, stream>>>((const f16x8*)Ahi, (const f16x8*)Alo,
                                   (const f16x8*)Bhi, (const f16x8*)Blo,
                                   cn2, cbT32, out, out + 4194307, partials);
  k_final<<<1, 256, 0, stream>>>(partials, out);
}